// Round 3
// baseline (167.436 us; speedup 1.0000x reference)
//
#include <hip/hip_runtime.h>

// ForwardKinematics: B samples, 24 joints, fixed SMPL parent tree. ALL fp32.
// rotations (B,24,4) quats wxyz, positions (B,24,3) -> global joint pos (B,24,3).
// One thread per sample; per-sample chunks are contiguous & 16B-aligned:
// rot 384 B (24x float4), pos 288 B (18x float4), out 288 B (18x float4).

#define NJ 24

__global__ __launch_bounds__(256) void fk_kernel(
    const float4* __restrict__ rot4,   // B*24 float4
    const float4* __restrict__ pos4,   // B*18 float4
    float4* __restrict__ out4,         // B*18 float4
    int B)
{
    const int b = blockIdx.x * blockDim.x + threadIdx.x;
    if (b >= B) return;

    const float4* rp = rot4 + (size_t)b * 24;
    const float4* pp = pos4 + (size_t)b * 18;

    // Load positions up front (18 float4 -> 72 floats) for memory-level parallelism.
    float t[72];
#pragma unroll
    for (int i = 0; i < 18; ++i) {
        float4 v = pp[i];
        t[4*i+0] = v.x; t[4*i+1] = v.y; t[4*i+2] = v.z; t[4*i+3] = v.w;
    }

    constexpr int PAR[NJ] = {-1, 0, 0, 0, 1, 2, 3, 4, 5, 6, 7, 8,
                              9, 9, 9, 12, 13, 14, 16, 17, 18, 19, 20, 21};

    float Gr[NJ][9];   // scalarized (static indices only)
    float Gt[NJ][3];

#pragma unroll
    for (int j = 0; j < NJ; ++j) {
        float4 qv = rp[j];                       // one quat = one float4
        float qw = qv.x, qx = qv.y, qy = qv.z, qz = qv.w;
        float px = t[3*j+0], py = t[3*j+1], pz = t[3*j+2];

        float inv = rsqrtf(qw*qw + qx*qx + qy*qy + qz*qz);
        qw *= inv; qx *= inv; qy *= inv; qz *= inv;

        float x2 = qx + qx, y2 = qy + qy, z2 = qz + qz;
        float xx = qx * x2, yy = qy * y2, zz = qz * z2;
        float xy = qx * y2, yz = qy * z2, xz = qx * z2;
        float wx = qw * x2, wy = qw * y2, wz = qw * z2;

        float lr[9] = {1.f - (yy + zz), xy - wz,         xz + wy,
                       xy + wz,         1.f - (xx + zz), yz - wx,
                       xz - wy,         yz + wx,         1.f - (xx + yy)};

        const int p = PAR[j];
        if (p < 0) {
#pragma unroll
            for (int k = 0; k < 9; ++k) Gr[j][k] = lr[k];
            Gt[j][0] = px; Gt[j][1] = py; Gt[j][2] = pz;
        } else {
            // G_j = G_p * L_j  (affine: R = Rp*Rl, t = Rp*tl + tp)
#pragma unroll
            for (int r = 0; r < 3; ++r) {
#pragma unroll
                for (int c = 0; c < 3; ++c) {
                    Gr[j][3*r+c] = Gr[p][3*r+0] * lr[0+c]
                                 + Gr[p][3*r+1] * lr[3+c]
                                 + Gr[p][3*r+2] * lr[6+c];
                }
                Gt[j][r] = Gr[p][3*r+0] * px
                         + Gr[p][3*r+1] * py
                         + Gr[p][3*r+2] * pz
                         + Gt[p][r];
            }
        }
    }

    // Output: 72 floats = 18 float4 stores. Element e -> Gt[e/3][e%3].
    float4* op = out4 + (size_t)b * 18;
#pragma unroll
    for (int i = 0; i < 18; ++i) {
        float4 v;
        v.x = Gt[(4*i+0)/3][(4*i+0)%3];
        v.y = Gt[(4*i+1)/3][(4*i+1)%3];
        v.z = Gt[(4*i+2)/3][(4*i+2)%3];
        v.w = Gt[(4*i+3)/3][(4*i+3)%3];
        op[i] = v;
    }
}

extern "C" void kernel_launch(void* const* d_in, const int* in_sizes, int n_in,
                              void* d_out, int out_size, void* d_ws, size_t ws_size,
                              hipStream_t stream) {
    // Output is (B,24,3) -> B = out_size/72. Resolve inputs BY SIZE, not order.
    const int B = out_size / 72;
    const void* rot = nullptr;
    const void* pos = nullptr;
    for (int i = 0; i < n_in; ++i) {
        if (in_sizes[i] == B * 96) rot = d_in[i];
        else if (in_sizes[i] == B * 72) pos = d_in[i];
    }
    if (!rot) rot = d_in[2];   // fallback: dict order (parents, positions, rotations)
    if (!pos) pos = d_in[1];

    const int block = 256;
    const int grid = (B + block - 1) / block;
    fk_kernel<<<grid, block, 0, stream>>>(
        (const float4*)rot, (const float4*)pos, (float4*)d_out, B);
}